// Round 1
// baseline (5231.000 us; speedup 1.0000x reference)
//
#include <hip/hip_runtime.h>
#include <hip/hip_bf16.h>

// DirectionalConvLayer on MI355X — MFMA + DPP-stats version, VALU-diet pass.
// x (8,64,256,256) f32, W (64,64,3,3) OIHW f32, b (64) f32.
// Height-1 rows with vpad 1 => width-3 1D conv using W[:,:,1,:] only.
// f[i] = elu(instnorm(conv(f[i-1]))) + x[i] forward; same backward over f.
// Bias omitted: InstanceNorm (no affine) exactly cancels per-channel shifts.
//
// One block per n (8 blocks, 512 threads = 8 waves). Conv as GEMM
// (M=64 o, N=256 w, K=192 (i,kw)) via v_mfma_f32_16x16x32_bf16; weights in
// 96 regs/lane for the whole kernel; B from transposed LDS row buf sFT[w][i].
// Stats: per-(mt,r) DPP row_shr add-trees (VALU only, no LDS port) -> lane 15
// holds each 16-lane w-sum; cross-wave reduce split 8 channels/wave.
//
// This round: (1) global loads/stores via row-invariant 32-bit BYTE offsets
// off a uniform scalar row base (saddr-form, no per-lane 64-bit adds);
// (2) normalize as single fmaf(acc, rstd, -mean*rstd); (3) fv folded into
// srcv (overwrite after consumption) to cut register pressure.

#define CC 64
#define HH 256
#define WW 256
#define PITCH 72  // bf16 elems per sFT row (144 B, 16B-aligned)

typedef short bf16x8 __attribute__((ext_vector_type(8)));
typedef short bf16x4 __attribute__((ext_vector_type(4)));
typedef float f32x4  __attribute__((ext_vector_type(4)));

// Tree-sum within each 16-lane row via DPP row_shr; lane 15 of the row holds
// the full 16-lane sum on return (other lanes hold partials).
__device__ __forceinline__ float row16_sum_tail(float v) {
    float acc = v;
    int s;
    s = __builtin_amdgcn_update_dpp(0, __builtin_bit_cast(int, acc), 0x111, 0xF, 0xF, true);
    acc += __builtin_bit_cast(float, s);
    s = __builtin_amdgcn_update_dpp(0, __builtin_bit_cast(int, acc), 0x112, 0xF, 0xF, true);
    acc += __builtin_bit_cast(float, s);
    s = __builtin_amdgcn_update_dpp(0, __builtin_bit_cast(int, acc), 0x114, 0xF, 0xF, true);
    acc += __builtin_bit_cast(float, s);
    s = __builtin_amdgcn_update_dpp(0, __builtin_bit_cast(int, acc), 0x118, 0xF, 0xF, true);
    acc += __builtin_bit_cast(float, s);
    return acc;
}

__global__ __launch_bounds__(512, 2) void dirconv_mfma(
    const float* __restrict__ x,
    const float* __restrict__ Wt,
    const float* __restrict__ bias,
    float* out)
{
    const int n    = blockIdx.x;
    const int t    = threadIdx.x;
    const int wave = t >> 6;
    const int lane = t & 63;
    const int quad = lane >> 4;
    const int l16  = lane & 15;
    const int w0   = wave * 32;

    __shared__ __hip_bfloat16 sFT[258 * PITCH];   // [w+1][i], pads at 0 and 257
    __shared__ float sRedS[8][CC];
    __shared__ float sRedQ[8][CC];
    __shared__ float sNMR[CC];    // -mean * rstd
    __shared__ float sRstd[CC];

    // ---- stage conv weights (middle kernel row) via LDS scratch (reuse sFT) ----
    __hip_bfloat16* sWs = sFT;  // [kw][i][o]
    for (int idx = t; idx < CC * CC * 9; idx += 512) {
        int o = idx / 576; int rem = idx - o * 576;
        int i = rem / 9;   int p   = rem - i * 9;
        if (p >= 3 && p < 6)
            sWs[((p - 3) * CC + i) * CC + o] = __float2bfloat16(Wt[idx]);
    }
    __syncthreads();

    // A frags: wA[mt][kw][q], elem j = W[o = mt*16+l16][i = q*32+quad*8+j]
    bf16x8 wA[4][3][2];
    for (int mt = 0; mt < 4; mt++)
        for (int kw = 0; kw < 3; kw++)
            for (int q = 0; q < 2; q++) {
                bf16x8 v;
                int o = mt * 16 + l16;
                #pragma unroll
                for (int j = 0; j < 8; j++) {
                    int i = q * 32 + quad * 8 + j;
                    v[j] = ((short*)sWs)[(kw * CC + i) * CC + o];
                }
                wA[mt][kw][q] = v;
            }
    __syncthreads();

    // ---- init: f0 = x row 0 -> sFT (bf16) and out (f32); zero pads ----
    const size_t nbase = (size_t)n * CC * HH * WW;
    for (int idx = t; idx < CC * WW; idx += 512) {
        int c = idx >> 8, w = idx & 255;
        float v = x[nbase + (size_t)c * (HH * WW) + w];
        sFT[(w + 1) * PITCH + c] = __float2bfloat16(v);
        out[nbase + (size_t)c * (HH * WW) + w] = v;
    }
    if (t < CC) {
        sFT[0 * PITCH + t]   = __float2bfloat16(0.f);
        sFT[257 * PITCH + t] = __float2bfloat16(0.f);
    }
    __syncthreads();

    // ---- row-invariant global BYTE offsets: o*(HH*WW) + w0 + l16, in bytes.
    // nt=1 is +16 floats = +64 bytes (folds into the load/store imm offset).
    unsigned gboff[4][4];
    #pragma unroll
    for (int mt = 0; mt < 4; mt++)
        #pragma unroll
        for (int r = 0; r < 4; r++)
            gboff[mt][r] = (unsigned)((((mt * 16 + quad * 4 + r) * (HH * WW))
                                       + w0 + l16) * 4);

    for (int phase = 0; phase < 2; phase++) {
        const float* src = (phase == 0) ? x : out;
        int row  = (phase == 0) ? 1 : HH - 2;
        int rend = (phase == 0) ? HH : -1;
        int rinc = (phase == 0) ? 1 : -1;

        const char* srcnb = (const char*)(src + nbase);
        char*       outnb = (char*)(out + nbase);

        for (; row != rend; row += rinc) {
            // uniform (scalar) row bases; all per-lane addressing is the
            // 32-bit gboff voffset -> saddr-form global loads/stores.
            const char* rowb = srcnb + (size_t)row * (WW * 4);
            char*       outb = outnb + (size_t)row * (WW * 4);

            // ---- prefetch src row (consumed in epilogue; hidden by conv) ----
            float srcv[2][4][4];
            #pragma unroll
            for (int mt = 0; mt < 4; mt++)
                #pragma unroll
                for (int r = 0; r < 4; r++) {
                    unsigned off = gboff[mt][r];
                    srcv[0][mt][r] = *(const float*)(rowb + off);
                    srcv[1][mt][r] = *(const float*)(rowb + off + 64);
                }

            // ---- conv via MFMA ----
            f32x4 acc[2][4];
            #pragma unroll
            for (int nt = 0; nt < 2; nt++)
                #pragma unroll
                for (int mt = 0; mt < 4; mt++)
                    acc[nt][mt] = (f32x4){0.f, 0.f, 0.f, 0.f};

            #pragma unroll
            for (int nt = 0; nt < 2; nt++) {
                int wr = w0 + nt * 16 + l16;
                #pragma unroll
                for (int kw = 0; kw < 3; kw++) {
                    const __hip_bfloat16* rp = &sFT[(wr + kw) * PITCH];
                    #pragma unroll
                    for (int q = 0; q < 2; q++) {
                        bf16x8 bf = *(const bf16x8*)(rp + q * 32 + quad * 8);
                        #pragma unroll
                        for (int mt = 0; mt < 4; mt++)
                            acc[nt][mt] = __builtin_amdgcn_mfma_f32_16x16x32_bf16(
                                wA[mt][kw][q], bf, acc[nt][mt], 0, 0, 0);
                    }
                }
            }

            // ---- stats via DPP trees (no LDS port) ----
            float sv[4][4], qv[4][4];
            #pragma unroll
            for (int mt = 0; mt < 4; mt++)
                #pragma unroll
                for (int r = 0; r < 4; r++) {
                    float a0 = acc[0][mt][r], a1 = acc[1][mt][r];
                    sv[mt][r] = row16_sum_tail(a0 + a1);
                    qv[mt][r] = row16_sum_tail(fmaf(a0, a0, a1 * a1));
                }
            if (l16 == 15) {
                #pragma unroll
                for (int mt = 0; mt < 4; mt++) {
                    *(f32x4*)&sRedS[wave][mt * 16 + quad * 4] =
                        (f32x4){sv[mt][0], sv[mt][1], sv[mt][2], sv[mt][3]};
                    *(f32x4*)&sRedQ[wave][mt * 16 + quad * 4] =
                        (f32x4){qv[mt][0], qv[mt][1], qv[mt][2], qv[mt][3]};
                }
            }
            __syncthreads();

            // ---- cross-wave reduce: wave w handles channels [8w, 8w+8) ----
            if (lane < 8) {
                int o = wave * 8 + lane;
                float s8 = 0.f, q8 = 0.f;
                #pragma unroll
                for (int j = 0; j < 8; j++) { s8 += sRedS[j][o]; q8 += sRedQ[j][o]; }
                float m   = s8 * (1.f / 256.f);
                float var = fmaf(m, -m, q8 * (1.f / 256.f));
                float rs  = rsqrtf(var + 1e-5f);
                sRstd[o] = rs;
                sNMR[o]  = -m * rs;
            }
            __syncthreads();

            // ---- epilogue: y = fma(acc, rstd, nmr); elu; +src; sFT; defer out ----
            #pragma unroll
            for (int mt = 0; mt < 4; mt++) {
                f32x4 nm = *(const f32x4*)&sNMR[mt * 16 + quad * 4];
                f32x4 rr = *(const f32x4*)&sRstd[mt * 16 + quad * 4];
                #pragma unroll
                for (int nt = 0; nt < 2; nt++) {
                    int w = w0 + nt * 16 + l16;
                    bf16x4 pk;
                    #pragma unroll
                    for (int r = 0; r < 4; r++) {
                        float y = fmaf(acc[nt][mt][r], rr[r], nm[r]);
                        y = (y > 0.f) ? y : (__expf(y) - 1.f);
                        float f = y + srcv[nt][mt][r];
                        srcv[nt][mt][r] = f;   // reuse regs: fv == srcv
                        union { __hip_bfloat16 h; short s; } cv;
                        cv.h = __float2bfloat16(f);
                        pk[r] = cv.s;
                    }
                    *(bf16x4*)&sFT[(w + 1) * PITCH + mt * 16 + quad * 4] = pk;
                }
            }
            __syncthreads();

            // ---- global stores after the barrier: drain overlaps next conv ----
            #pragma unroll
            for (int mt = 0; mt < 4; mt++)
                #pragma unroll
                for (int r = 0; r < 4; r++) {
                    unsigned off = gboff[mt][r];
                    *(float*)(outb + off)      = srcv[0][mt][r];
                    *(float*)(outb + off + 64) = srcv[1][mt][r];
                }
        }
    }
}

extern "C" void kernel_launch(void* const* d_in, const int* in_sizes, int n_in,
                              void* d_out, int out_size, void* d_ws, size_t ws_size,
                              hipStream_t stream) {
    const float* x  = (const float*)d_in[0];
    const float* Wt = (const float*)d_in[1];
    const float* b  = (const float*)d_in[2];
    float* out = (float*)d_out;
    dirconv_mfma<<<8, 512, 0, stream>>>(x, Wt, b, out);
}

// Round 2
// 4723.140 us; speedup vs baseline: 1.1075x; 1.1075x over previous
//
#include <hip/hip_runtime.h>
#include <hip/hip_bf16.h>

// DirectionalConvLayer on MI355X — MFMA + DPP-stats version.
// x (8,64,256,256) f32, W (64,64,3,3) OIHW f32, b (64) f32.
// Height-1 rows with vpad 1 => width-3 1D conv using W[:,:,1,:] only.
// f[i] = elu(instnorm(conv(f[i-1]))) + x[i] forward; same backward over f.
// Bias omitted: InstanceNorm (no affine) exactly cancels per-channel shifts.
//
// One block per n (8 blocks, 512 threads = 8 waves). Conv as GEMM
// (M=64 o, N=256 w, K=192 (i,kw)) via v_mfma_f32_16x16x32_bf16; weights in
// 96 regs/lane for the whole kernel; B from transposed LDS row buf sFT[w][i].
// Stats: per-(mt,r) DPP row_shr add-trees (VALU only, no LDS port) -> lane 15
// holds each 16-lane w-sum; cross-wave reduce split 8 channels/wave.
//
// Round-2 lesson: cheap saddr-form addressing + extended srcv live range let
// the scheduler SINK the prefetch loads into the epilogue (serialized ~900cy
// latency per use, +14k cy/row, 2.5x slower). Fix: keep cheap 32-bit gboff
// addressing but (a) restore separate fv array (round-0 live ranges),
// (b) pin load issue with sched_barrier(0) right after the prefetch,
// (c) keep-alive asm uses of srcv after the MFMA block so loads must have
// completed there (latency hidden under conv, sinking impossible).

#define CC 64
#define HH 256
#define WW 256
#define PITCH 72  // bf16 elems per sFT row (144 B, 16B-aligned)

typedef short bf16x8 __attribute__((ext_vector_type(8)));
typedef short bf16x4 __attribute__((ext_vector_type(4)));
typedef float f32x4  __attribute__((ext_vector_type(4)));

// Tree-sum within each 16-lane row via DPP row_shr; lane 15 of the row holds
// the full 16-lane sum on return (other lanes hold partials).
__device__ __forceinline__ float row16_sum_tail(float v) {
    float acc = v;
    int s;
    s = __builtin_amdgcn_update_dpp(0, __builtin_bit_cast(int, acc), 0x111, 0xF, 0xF, true);
    acc += __builtin_bit_cast(float, s);
    s = __builtin_amdgcn_update_dpp(0, __builtin_bit_cast(int, acc), 0x112, 0xF, 0xF, true);
    acc += __builtin_bit_cast(float, s);
    s = __builtin_amdgcn_update_dpp(0, __builtin_bit_cast(int, acc), 0x114, 0xF, 0xF, true);
    acc += __builtin_bit_cast(float, s);
    s = __builtin_amdgcn_update_dpp(0, __builtin_bit_cast(int, acc), 0x118, 0xF, 0xF, true);
    acc += __builtin_bit_cast(float, s);
    return acc;
}

__global__ __launch_bounds__(512, 2) void dirconv_mfma(
    const float* __restrict__ x,
    const float* __restrict__ Wt,
    const float* __restrict__ bias,
    float* out)
{
    const int n    = blockIdx.x;
    const int t    = threadIdx.x;
    const int wave = t >> 6;
    const int lane = t & 63;
    const int quad = lane >> 4;
    const int l16  = lane & 15;
    const int w0   = wave * 32;

    __shared__ __hip_bfloat16 sFT[258 * PITCH];   // [w+1][i], pads at 0 and 257
    __shared__ float sRedS[8][CC];
    __shared__ float sRedQ[8][CC];
    __shared__ float sNMR[CC];    // -mean * rstd
    __shared__ float sRstd[CC];

    // ---- stage conv weights (middle kernel row) via LDS scratch (reuse sFT) ----
    __hip_bfloat16* sWs = sFT;  // [kw][i][o]
    for (int idx = t; idx < CC * CC * 9; idx += 512) {
        int o = idx / 576; int rem = idx - o * 576;
        int i = rem / 9;   int p   = rem - i * 9;
        if (p >= 3 && p < 6)
            sWs[((p - 3) * CC + i) * CC + o] = __float2bfloat16(Wt[idx]);
    }
    __syncthreads();

    // A frags: wA[mt][kw][q], elem j = W[o = mt*16+l16][i = q*32+quad*8+j]
    bf16x8 wA[4][3][2];
    for (int mt = 0; mt < 4; mt++)
        for (int kw = 0; kw < 3; kw++)
            for (int q = 0; q < 2; q++) {
                bf16x8 v;
                int o = mt * 16 + l16;
                #pragma unroll
                for (int j = 0; j < 8; j++) {
                    int i = q * 32 + quad * 8 + j;
                    v[j] = ((short*)sWs)[(kw * CC + i) * CC + o];
                }
                wA[mt][kw][q] = v;
            }
    __syncthreads();

    // ---- init: f0 = x row 0 -> sFT (bf16) and out (f32); zero pads ----
    const size_t nbase = (size_t)n * CC * HH * WW;
    for (int idx = t; idx < CC * WW; idx += 512) {
        int c = idx >> 8, w = idx & 255;
        float v = x[nbase + (size_t)c * (HH * WW) + w];
        sFT[(w + 1) * PITCH + c] = __float2bfloat16(v);
        out[nbase + (size_t)c * (HH * WW) + w] = v;
    }
    if (t < CC) {
        sFT[0 * PITCH + t]   = __float2bfloat16(0.f);
        sFT[257 * PITCH + t] = __float2bfloat16(0.f);
    }
    __syncthreads();

    // ---- row-invariant global BYTE offsets: o*(HH*WW) + w0 + l16, in bytes.
    // nt=1 is +16 floats = +64 bytes (folds into the load/store imm offset).
    unsigned gboff[4][4];
    #pragma unroll
    for (int mt = 0; mt < 4; mt++)
        #pragma unroll
        for (int r = 0; r < 4; r++)
            gboff[mt][r] = (unsigned)((((mt * 16 + quad * 4 + r) * (HH * WW))
                                       + w0 + l16) * 4);

    for (int phase = 0; phase < 2; phase++) {
        const float* src = (phase == 0) ? x : out;
        int row  = (phase == 0) ? 1 : HH - 2;
        int rend = (phase == 0) ? HH : -1;
        int rinc = (phase == 0) ? 1 : -1;

        const char* srcnb = (const char*)(src + nbase);
        char*       outnb = (char*)(out + nbase);

        for (; row != rend; row += rinc) {
            const char* rowb = srcnb + (size_t)row * (WW * 4);
            char*       outb = outnb + (size_t)row * (WW * 4);

            // ---- prefetch src row (consumed in epilogue; hidden by conv) ----
            float srcv[2][4][4];
            #pragma unroll
            for (int mt = 0; mt < 4; mt++)
                #pragma unroll
                for (int r = 0; r < 4; r++) {
                    unsigned off = gboff[mt][r];
                    srcv[0][mt][r] = *(const float*)(rowb + off);
                    srcv[1][mt][r] = *(const float*)(rowb + off + 64);
                }
            // Pin the load issue point: nothing may cross this barrier, so
            // the loads above cannot be sunk below the conv.
            __builtin_amdgcn_sched_barrier(0);

            // ---- conv via MFMA ----
            f32x4 acc[2][4];
            #pragma unroll
            for (int nt = 0; nt < 2; nt++)
                #pragma unroll
                for (int mt = 0; mt < 4; mt++)
                    acc[nt][mt] = (f32x4){0.f, 0.f, 0.f, 0.f};

            #pragma unroll
            for (int nt = 0; nt < 2; nt++) {
                int wr = w0 + nt * 16 + l16;
                #pragma unroll
                for (int kw = 0; kw < 3; kw++) {
                    const __hip_bfloat16* rp = &sFT[(wr + kw) * PITCH];
                    #pragma unroll
                    for (int q = 0; q < 2; q++) {
                        bf16x8 bf = *(const bf16x8*)(rp + q * 32 + quad * 8);
                        #pragma unroll
                        for (int mt = 0; mt < 4; mt++)
                            acc[nt][mt] = __builtin_amdgcn_mfma_f32_16x16x32_bf16(
                                wA[mt][kw][q], bf, acc[nt][mt], 0, 0, 0);
                    }
                }
            }

            // Keep-alive: force every srcv load to have completed here (one
            // pipelined waitcnt, latency hidden under the conv above). This
            // makes sinking into the epilogue impossible at any pass.
            #pragma unroll
            for (int nt = 0; nt < 2; nt++)
                #pragma unroll
                for (int mt = 0; mt < 4; mt++)
                    #pragma unroll
                    for (int r = 0; r < 4; r++)
                        asm volatile("" : "+v"(srcv[nt][mt][r]));

            // ---- stats via DPP trees (no LDS port) ----
            float sv[4][4], qv[4][4];
            #pragma unroll
            for (int mt = 0; mt < 4; mt++)
                #pragma unroll
                for (int r = 0; r < 4; r++) {
                    float a0 = acc[0][mt][r], a1 = acc[1][mt][r];
                    sv[mt][r] = row16_sum_tail(a0 + a1);
                    qv[mt][r] = row16_sum_tail(fmaf(a0, a0, a1 * a1));
                }
            if (l16 == 15) {
                #pragma unroll
                for (int mt = 0; mt < 4; mt++) {
                    *(f32x4*)&sRedS[wave][mt * 16 + quad * 4] =
                        (f32x4){sv[mt][0], sv[mt][1], sv[mt][2], sv[mt][3]};
                    *(f32x4*)&sRedQ[wave][mt * 16 + quad * 4] =
                        (f32x4){qv[mt][0], qv[mt][1], qv[mt][2], qv[mt][3]};
                }
            }
            __syncthreads();

            // ---- cross-wave reduce: wave w handles channels [8w, 8w+8) ----
            if (lane < 8) {
                int o = wave * 8 + lane;
                float s8 = 0.f, q8 = 0.f;
                #pragma unroll
                for (int j = 0; j < 8; j++) { s8 += sRedS[j][o]; q8 += sRedQ[j][o]; }
                float m   = s8 * (1.f / 256.f);
                float var = fmaf(m, -m, q8 * (1.f / 256.f));
                float rs  = rsqrtf(var + 1e-5f);
                sRstd[o] = rs;
                sNMR[o]  = -m * rs;
            }
            __syncthreads();

            // ---- epilogue: y = fma(acc, rstd, nmr); elu; +src; sFT; defer out ----
            float fv[2][4][4];
            #pragma unroll
            for (int mt = 0; mt < 4; mt++) {
                f32x4 nm = *(const f32x4*)&sNMR[mt * 16 + quad * 4];
                f32x4 rr = *(const f32x4*)&sRstd[mt * 16 + quad * 4];
                #pragma unroll
                for (int nt = 0; nt < 2; nt++) {
                    int w = w0 + nt * 16 + l16;
                    bf16x4 pk;
                    #pragma unroll
                    for (int r = 0; r < 4; r++) {
                        float y = fmaf(acc[nt][mt][r], rr[r], nm[r]);
                        y = (y > 0.f) ? y : (__expf(y) - 1.f);
                        float f = y + srcv[nt][mt][r];
                        fv[nt][mt][r] = f;
                        union { __hip_bfloat16 h; short s; } cv;
                        cv.h = __float2bfloat16(f);
                        pk[r] = cv.s;
                    }
                    *(bf16x4*)&sFT[(w + 1) * PITCH + mt * 16 + quad * 4] = pk;
                }
            }
            __syncthreads();

            // ---- global stores after the barrier: drain overlaps next conv ----
            #pragma unroll
            for (int mt = 0; mt < 4; mt++)
                #pragma unroll
                for (int r = 0; r < 4; r++) {
                    unsigned off = gboff[mt][r];
                    *(float*)(outb + off)      = fv[0][mt][r];
                    *(float*)(outb + off + 64) = fv[1][mt][r];
                }
        }
    }
}

extern "C" void kernel_launch(void* const* d_in, const int* in_sizes, int n_in,
                              void* d_out, int out_size, void* d_ws, size_t ws_size,
                              hipStream_t stream) {
    const float* x  = (const float*)d_in[0];
    const float* Wt = (const float*)d_in[1];
    const float* b  = (const float*)d_in[2];
    float* out = (float*)d_out;
    dirconv_mfma<<<8, 512, 0, stream>>>(x, Wt, b, out);
}

// Round 5
// 2092.677 us; speedup vs baseline: 2.4997x; 2.2570x over previous
//
#include <hip/hip_runtime.h>
#include <hip/hip_bf16.h>

// DirectionalConvLayer on MI355X — MFMA + DPP-stats version.
// x (8,64,256,256) f32, W (64,64,3,3) OIHW f32, b (64) f32.
// Height-1 rows with vpad 1 => width-3 1D conv using W[:,:,1,:] only.
// f[i] = elu(instnorm(conv(f[i-1]))) + x[i] forward; same backward over f.
// Bias omitted: InstanceNorm (no affine) exactly cancels per-channel shifts.
//
// One block per n (8 blocks, 512 threads = 8 waves). Conv as GEMM
// (M=64 o, N=256 w, K=192 (i,kw)) via v_mfma_f32_16x16x32_bf16; weights in
// 96 VGPRs/lane for the whole kernel; B from transposed LDS row buf sFT[w][i].
// Stats: per-(mt,r) DPP row_shr add-trees (VALU only, no LDS port) -> lane 15
// holds each 16-lane w-sum; cross-wave reduce split 8 channels/wave.
// Global out-stores issued after the last barrier (drain overlaps next conv).
//
// NOTE (rounds 1-2 lesson): rewriting load/store addressing to uniform-base +
// 32-bit byte-offset tables (saddr form) caused a pure-stall 2.25x regression
// (identical VALU/MFMA work, +12k stall cy/row) that persisted even with the
// loads pinned before the conv. Keep the round-0 64-bit inline indexing —
// the compiler's schedule for it is proven. Only local arithmetic changes
// here: normalize via single fmaf (sNMR = -mean*rstd published by reducer).
//
// (Rounds 3-4 benches were infra failures — container acquisition; identical
// kernel resubmitted.)

#define CC 64
#define HH 256
#define WW 256
#define PITCH 72  // bf16 elems per sFT row (144 B, 16B-aligned)

typedef short bf16x8 __attribute__((ext_vector_type(8)));
typedef short bf16x4 __attribute__((ext_vector_type(4)));
typedef float f32x4  __attribute__((ext_vector_type(4)));

// Tree-sum within each 16-lane row via DPP row_shr; lane 15 of the row holds
// the full 16-lane sum on return (other lanes hold partials).
__device__ __forceinline__ float row16_sum_tail(float v) {
    float acc = v;
    int s;
    s = __builtin_amdgcn_update_dpp(0, __builtin_bit_cast(int, acc), 0x111, 0xF, 0xF, true);
    acc += __builtin_bit_cast(float, s);
    s = __builtin_amdgcn_update_dpp(0, __builtin_bit_cast(int, acc), 0x112, 0xF, 0xF, true);
    acc += __builtin_bit_cast(float, s);
    s = __builtin_amdgcn_update_dpp(0, __builtin_bit_cast(int, acc), 0x114, 0xF, 0xF, true);
    acc += __builtin_bit_cast(float, s);
    s = __builtin_amdgcn_update_dpp(0, __builtin_bit_cast(int, acc), 0x118, 0xF, 0xF, true);
    acc += __builtin_bit_cast(float, s);
    return acc;
}

__global__ __launch_bounds__(512, 2) void dirconv_mfma(
    const float* __restrict__ x,
    const float* __restrict__ Wt,
    const float* __restrict__ bias,
    float* out)
{
    const int n    = blockIdx.x;
    const int t    = threadIdx.x;
    const int wave = t >> 6;
    const int lane = t & 63;
    const int quad = lane >> 4;
    const int l16  = lane & 15;
    const int w0   = wave * 32;

    __shared__ __hip_bfloat16 sFT[258 * PITCH];   // [w+1][i], pads at 0 and 257
    __shared__ float sRedS[8][CC];
    __shared__ float sRedQ[8][CC];
    __shared__ float sNMR[CC];    // -mean * rstd
    __shared__ float sRstd[CC];

    // ---- stage conv weights (middle kernel row) via LDS scratch (reuse sFT) ----
    __hip_bfloat16* sWs = sFT;  // [kw][i][o]
    for (int idx = t; idx < CC * CC * 9; idx += 512) {
        int o = idx / 576; int rem = idx - o * 576;
        int i = rem / 9;   int p   = rem - i * 9;
        if (p >= 3 && p < 6)
            sWs[((p - 3) * CC + i) * CC + o] = __float2bfloat16(Wt[idx]);
    }
    __syncthreads();

    // A frags: wA[mt][kw][q], elem j = W[o = mt*16+l16][i = q*32+quad*8+j]
    bf16x8 wA[4][3][2];
    for (int mt = 0; mt < 4; mt++)
        for (int kw = 0; kw < 3; kw++)
            for (int q = 0; q < 2; q++) {
                bf16x8 v;
                int o = mt * 16 + l16;
                #pragma unroll
                for (int j = 0; j < 8; j++) {
                    int i = q * 32 + quad * 8 + j;
                    v[j] = ((short*)sWs)[(kw * CC + i) * CC + o];
                }
                wA[mt][kw][q] = v;
            }
    __syncthreads();

    // ---- init: f0 = x row 0 -> sFT (bf16) and out (f32); zero pads ----
    const size_t nbase = (size_t)n * CC * HH * WW;
    for (int idx = t; idx < CC * WW; idx += 512) {
        int c = idx >> 8, w = idx & 255;
        float v = x[nbase + (size_t)c * (HH * WW) + w];
        sFT[(w + 1) * PITCH + c] = __float2bfloat16(v);
        out[nbase + (size_t)c * (HH * WW) + w] = v;
    }
    if (t < CC) {
        sFT[0 * PITCH + t]   = __float2bfloat16(0.f);
        sFT[257 * PITCH + t] = __float2bfloat16(0.f);
    }
    __syncthreads();

    for (int phase = 0; phase < 2; phase++) {
        const float* src = (phase == 0) ? x : out;
        int row  = (phase == 0) ? 1 : HH - 2;
        int rend = (phase == 0) ? HH : -1;
        int rinc = (phase == 0) ? 1 : -1;

        for (; row != rend; row += rinc) {
            const size_t rowbase = nbase + (size_t)row * WW;

            // ---- prefetch src row (consumed in epilogue; hidden by conv) ----
            float srcv[2][4][4];
            #pragma unroll
            for (int nt = 0; nt < 2; nt++) {
                int w = w0 + nt * 16 + l16;
                #pragma unroll
                for (int mt = 0; mt < 4; mt++)
                    #pragma unroll
                    for (int r = 0; r < 4; r++) {
                        int o = mt * 16 + quad * 4 + r;
                        srcv[nt][mt][r] = src[rowbase + (size_t)o * (HH * WW) + w];
                    }
            }

            // ---- conv via MFMA ----
            f32x4 acc[2][4];
            #pragma unroll
            for (int nt = 0; nt < 2; nt++)
                #pragma unroll
                for (int mt = 0; mt < 4; mt++)
                    acc[nt][mt] = (f32x4){0.f, 0.f, 0.f, 0.f};

            #pragma unroll
            for (int nt = 0; nt < 2; nt++) {
                int wr = w0 + nt * 16 + l16;
                #pragma unroll
                for (int kw = 0; kw < 3; kw++) {
                    const __hip_bfloat16* rp = &sFT[(wr + kw) * PITCH];
                    #pragma unroll
                    for (int q = 0; q < 2; q++) {
                        bf16x8 bf = *(const bf16x8*)(rp + q * 32 + quad * 8);
                        #pragma unroll
                        for (int mt = 0; mt < 4; mt++)
                            acc[nt][mt] = __builtin_amdgcn_mfma_f32_16x16x32_bf16(
                                wA[mt][kw][q], bf, acc[nt][mt], 0, 0, 0);
                    }
                }
            }

            // ---- stats via DPP trees (no LDS port) ----
            float sv[4][4], qv[4][4];
            #pragma unroll
            for (int mt = 0; mt < 4; mt++)
                #pragma unroll
                for (int r = 0; r < 4; r++) {
                    float a0 = acc[0][mt][r], a1 = acc[1][mt][r];
                    sv[mt][r] = row16_sum_tail(a0 + a1);
                    qv[mt][r] = row16_sum_tail(fmaf(a0, a0, a1 * a1));
                }
            if (l16 == 15) {
                #pragma unroll
                for (int mt = 0; mt < 4; mt++) {
                    *(f32x4*)&sRedS[wave][mt * 16 + quad * 4] =
                        (f32x4){sv[mt][0], sv[mt][1], sv[mt][2], sv[mt][3]};
                    *(f32x4*)&sRedQ[wave][mt * 16 + quad * 4] =
                        (f32x4){qv[mt][0], qv[mt][1], qv[mt][2], qv[mt][3]};
                }
            }
            __syncthreads();

            // ---- cross-wave reduce: wave w handles channels [8w, 8w+8) ----
            if (lane < 8) {
                int o = wave * 8 + lane;
                float s8 = 0.f, q8 = 0.f;
                #pragma unroll
                for (int j = 0; j < 8; j++) { s8 += sRedS[j][o]; q8 += sRedQ[j][o]; }
                float m   = s8 * (1.f / 256.f);
                float var = fmaf(m, -m, q8 * (1.f / 256.f));
                float rs  = rsqrtf(var + 1e-5f);
                sRstd[o] = rs;
                sNMR[o]  = -m * rs;
            }
            __syncthreads();

            // ---- epilogue: y = fma(acc, rstd, nmr); elu; +src; sFT; defer out ----
            float fv[2][4][4];
            #pragma unroll
            for (int mt = 0; mt < 4; mt++) {
                f32x4 nm = *(const f32x4*)&sNMR[mt * 16 + quad * 4];
                f32x4 rr = *(const f32x4*)&sRstd[mt * 16 + quad * 4];
                #pragma unroll
                for (int nt = 0; nt < 2; nt++) {
                    int w = w0 + nt * 16 + l16;
                    bf16x4 pk;
                    #pragma unroll
                    for (int r = 0; r < 4; r++) {
                        float y = fmaf(acc[nt][mt][r], rr[r], nm[r]);
                        y = (y > 0.f) ? y : (__expf(y) - 1.f);
                        float f = y + srcv[nt][mt][r];
                        fv[nt][mt][r] = f;
                        union { __hip_bfloat16 h; short s; } cv;
                        cv.h = __float2bfloat16(f);
                        pk[r] = cv.s;
                    }
                    *(bf16x4*)&sFT[(w + 1) * PITCH + mt * 16 + quad * 4] = pk;
                }
            }
            __syncthreads();

            // ---- global stores after the barrier: drain overlaps next conv ----
            #pragma unroll
            for (int nt = 0; nt < 2; nt++) {
                int w = w0 + nt * 16 + l16;
                #pragma unroll
                for (int mt = 0; mt < 4; mt++)
                    #pragma unroll
                    for (int r = 0; r < 4; r++) {
                        int o = mt * 16 + quad * 4 + r;
                        out[rowbase + (size_t)o * (HH * WW) + w] = fv[nt][mt][r];
                    }
            }
        }
    }
}

extern "C" void kernel_launch(void* const* d_in, const int* in_sizes, int n_in,
                              void* d_out, int out_size, void* d_ws, size_t ws_size,
                              hipStream_t stream) {
    const float* x  = (const float*)d_in[0];
    const float* Wt = (const float*)d_in[1];
    const float* b  = (const float*)d_in[2];
    float* out = (float*)d_out;
    dirconv_mfma<<<8, 512, 0, stream>>>(x, Wt, b, out);
}